// Round 11
// baseline (265.941 us; speedup 1.0000x reference)
//
#include <hip/hip_runtime.h>

#define D 128          // D_IN == D_OUT == 128
#define NREL 4
#define BINSHIFT 7     // 128 buckets per bin = 32 dsts x 4 rels (M=32 tile).
                       // 3125 bins -> 12.2 blocks/CU available vs 8-block cap,
                       // so agg residency pegs at the wave limit (r10: 1563
                       // bins = 6.1/CU was the 56%-occupancy cap).
#define NBK 128        // buckets per bin
#define BCAP 896       // edge capacity per bin window (mean 640, +10 sigma)
#define BPAD 32        // ints per counter slot (128 B = 1 L2 line; r5/r6: same-
                       // line atomics serialize ~225 cy EACH, latency not tput)
#define NSCAT 128      // scatter blocks x 1024 thr. Reserve atomics =
                       // NSCAT*nbins ~= 400K (same count as r9's best config).
#define NBINS_MAX 3200

typedef __attribute__((ext_vector_type(8))) short short8;
typedef __attribute__((ext_vector_type(4))) float f32x4;

static __device__ inline unsigned short f2bf(float f) {
    unsigned int u = __float_as_uint(f);
    u += 0x7fffu + ((u >> 16) & 1u);   // round-to-nearest-even
    return (unsigned short)(u >> 16);
}

// ---------------------------------------------------------------------------
// part1 + prep, two-pass batched scatter, 1024-thread blocks.
// Bucket key DST-MAJOR: g = dst*4+rel; one bin = 32 dsts x 4 rels.
//  A) blocks 0..NSCAT-1, chunk = ceil(total/NSCAT) edges:
//     pass1: LDS histogram (3125 bins, LDS atomics, 12.8 KB);
//     reserve: ONE global atomicAdd per non-empty bin -> absolute cursor;
//     pass2: re-read chunk (L2-hot), place via LDS cursor++, scattered store.
//  B) all blocks: grid-stride xcast (f32->bf16), W swizzle, bias sum.
// Entry = src | (g&127)<<17, bin = g>>7.
// ---------------------------------------------------------------------------
__global__ __launch_bounds__(1024) void part1prep_kernel(
    const float* __restrict__ x,      // [N][128]
    const float* __restrict__ W,      // [4][128][128]
    const float* __restrict__ bias,   // [4][128]
    const int* __restrict__ src, const int* __restrict__ dst,
    int* __restrict__ binCnt, unsigned int* __restrict__ part,
    unsigned short* __restrict__ xB,  // [N][128] bf16
    unsigned short* __restrict__ Wsw, // [16][8][64][8] bf16
    float* __restrict__ bsum,         // [128]
    int E, int N, int nbins, int total)
{
    __shared__ int hist[NBINS_MAX];   // 12.8 KB: count -> absolute cursor

    const int t     = threadIdx.x;
    const int gtid  = blockIdx.x * 1024 + t;
    const int gsize = gridDim.x * 1024;
    const int E2 = 2 * E, E3 = 3 * E;

    // ================= Phase A: batched scatter (blocks < NSCAT) ===========
    if (blockIdx.x < NSCAT) {
        const int chunk = (total + NSCAT - 1) / NSCAT;   // 15625
        const int e0 = blockIdx.x * chunk;
        const int n  = min(chunk, total - e0);

        for (int i = t; i < nbins; i += 1024) hist[i] = 0;
        __syncthreads();

        // pass 1: count (coalesced dst read)
        for (int i = t; i < n; i += 1024) {
            const int e = e0 + i;
            const int g = (dst[e] << 2) | ((e >= E) + (e >= E2) + (e >= E3));
            atomicAdd(&hist[g >> BINSHIFT], 1);
        }
        __syncthreads();

        // reserve: one global atomic per non-empty bin -> ABSOLUTE cursor
        for (int b = t; b < nbins; b += 1024) {
            const int h = hist[b];
            hist[b] = h ? b * BCAP + atomicAdd(&binCnt[b * BPAD], h) : 0;
        }
        __syncthreads();

        // pass 2: re-read (L2-hot), place via LDS cursor
        for (int i = t; i < n; i += 1024) {
            const int e = e0 + i;
            const int g = (dst[e] << 2) | ((e >= E) + (e >= E2) + (e >= E3));
            const int bin = g >> BINSHIFT;
            const unsigned entry = (unsigned)src[e] | ((unsigned)(g & (NBK - 1)) << 17);
            const int pos = atomicAdd(&hist[bin], 1);        // LDS cursor
            if (pos < (bin + 1) * BCAP)                      // 10-sigma guard
                part[pos] = entry;
        }
    }

    // ================= Phase B: prep (all blocks, grid-stride) ==============
    if (gtid < D)
        bsum[gtid] = bias[gtid] + bias[D + gtid] + bias[2 * D + gtid] + bias[3 * D + gtid];

    for (int gid = gtid; gid < 8192; gid += gsize) {
        const int l   = gid & 63;
        const int ct  = (gid >> 6) & 7;
        const int kb  = gid >> 9;
        const int rel = kb >> 2;
        const int kbase = (kb & 3) * 32 + (l >> 4) * 8;
        const int nn = ct * 16 + (l & 15);
        ushort4 v0, v1;
        const float* wp = W + (size_t)rel * D * D + (size_t)kbase * D + nn;
        v0.x = f2bf(wp[0 * D]); v0.y = f2bf(wp[1 * D]);
        v0.z = f2bf(wp[2 * D]); v0.w = f2bf(wp[3 * D]);
        v1.x = f2bf(wp[4 * D]); v1.y = f2bf(wp[5 * D]);
        v1.z = f2bf(wp[6 * D]); v1.w = f2bf(wp[7 * D]);
        ushort4* op = (ushort4*)(Wsw + (size_t)gid * 8);
        op[0] = v0;
        op[1] = v1;
    }

    const int n4 = N * D / 4;
    for (int i = gtid; i < n4; i += gsize) {
        const float4 v = ((const float4*)x)[i];
        ushort4 o;
        o.x = f2bf(v.x); o.y = f2bf(v.y); o.z = f2bf(v.z); o.w = f2bf(v.w);
        ((ushort4*)xB)[i] = o;
    }
}

// ---------------------------------------------------------------------------
// Fused aggregate + GEMM + bias + ReLU. ONE block per bin (M=32 dsts).
//  A) read part[] ONCE: 128-bucket histogram + raw staging into the idle agg
//     region (3.6 <= 8 KB); scan; LDS counting-sort into sh_s[896].
//  B/C) 4 rel-quarters: gather rel q's 32 buckets -> bf16 LDS tile
//     agg[32][128] (XOR-swizzled), sync, 4-kb MFMA pass into VGPR acc[2][2],
//     sync. Epilogue: bias + ReLU + f32 store.
// LDS ~13.8 KB -> 8 blocks/CU (wave cap); grid 3125 = 12.2/CU available so
// residency stays pegged at the cap (r10's 6.1/CU grid was the 56% limit).
// ---------------------------------------------------------------------------
__global__ __launch_bounds__(256, 8) void agg_gemm_kernel(
    const unsigned int* __restrict__ part,
    const int* __restrict__ binCnt,
    const unsigned short* __restrict__ xB,   // [N][128] bf16
    const unsigned short* __restrict__ Wsw,  // [16][8][64][8] bf16
    const float* __restrict__ bsum,          // [128]
    float* __restrict__ out,                 // [N][128]
    int N)
{
    __shared__ int sh_s[BCAP];                         // 3.6 KB sorted src
    __shared__ int hist[NBK];                          // 0.5 KB
    __shared__ int scanbuf[256];                       // 1 KB
    __shared__ int offl[NBK + 1];                      // 0.5 KB
    __shared__ __align__(16) unsigned short agg[32 * 128];  // 8 KB, swizzled
    // phase-A overlay: raw entry staging in the idle agg region (3.6 <= 8 KB)
    unsigned int* raw = (unsigned int*)agg;

    const int t    = threadIdx.x;
    const int b    = blockIdx.x;
    const size_t base = (size_t)b * BCAP;
    const int cnt  = min(binCnt[b * BPAD], BCAP);
    const int dst0 = b * 32;

    // ---- A: histogram + raw staging (single part[] read) ----
    if (t < NBK) hist[t] = 0;
    __syncthreads();
    for (int i = t; i < cnt; i += 256) {
        const unsigned v = part[base + i];
        raw[i] = v;
        atomicAdd(&hist[v >> 17], 1);
    }
    __syncthreads();

    const int myc = (t < NBK) ? hist[t] : 0;
    scanbuf[t] = myc;
    __syncthreads();
    for (int off = 1; off < NBK; off <<= 1) {
        int v = (t >= off) ? scanbuf[t - off] : 0;
        __syncthreads();
        scanbuf[t] += v;
        __syncthreads();
    }
    if (t < NBK) {
        offl[t] = scanbuf[t] - myc;
        hist[t] = scanbuf[t] - myc;       // cursor
    }
    if (t == NBK - 1) offl[NBK] = scanbuf[NBK - 1];
    __syncthreads();

    // sort: LDS raw -> LDS sh_s
    for (int i = t; i < cnt; i += 256) {
        const unsigned v = raw[i];
        const int pos = atomicAdd(&hist[v >> 17], 1);
        sh_s[pos] = (int)(v & 0x1FFFF);
    }
    __syncthreads();

    // ---- B/C: 4 rel-quarters of gather -> LDS -> MFMA ----
    const int c    = t & 15;        // 16-byte chunk index (8 bf16)
    const int team = t >> 4;        // unit slot 0..15

    const int wv   = t >> 6;
    const int l    = t & 63;
    const int lrow = l & 15;
    const int quad = l >> 4;
    const int ct0  = wv * 2;        // each wave: 2 col-tiles x 2 row-tiles

    f32x4 acc[2][2] = {};

    #define ACCUM(v)                                        \
        accL[0] += __uint_as_float((v).x << 16);            \
        accH[0] += __uint_as_float((v).x & 0xffff0000u);    \
        accL[1] += __uint_as_float((v).y << 16);            \
        accH[1] += __uint_as_float((v).y & 0xffff0000u);    \
        accL[2] += __uint_as_float((v).z << 16);            \
        accH[2] += __uint_as_float((v).z & 0xffff0000u);    \
        accL[3] += __uint_as_float((v).w << 16);            \
        accH[3] += __uint_as_float((v).w & 0xffff0000u);

    #pragma unroll 1
    for (int q = 0; q < NREL; ++q) {
        if (q) __syncthreads();       // previous MFMA pass done with agg

        // gather: 32 buckets of rel q (bucket = ld*4 + q)
        for (int ld = team; ld < 32; ld += 16) {
            const int bkt = ld * 4 + q;
            const int beg = offl[bkt];
            const int end = offl[bkt + 1];
            const float inv = 1.0f / fmaxf((float)(end - beg), 1.0f);

            float accL[4] = {0.f, 0.f, 0.f, 0.f};
            float accH[4] = {0.f, 0.f, 0.f, 0.f};

            int j = beg;
            for (; j + 3 < end; j += 4) {
                const int s0 = sh_s[j];
                const int s1 = sh_s[j + 1];
                const int s2 = sh_s[j + 2];
                const int s3 = sh_s[j + 3];
                const uint4 v0 = *(const uint4*)(xB + (size_t)s0 * D + c * 8);
                const uint4 v1 = *(const uint4*)(xB + (size_t)s1 * D + c * 8);
                const uint4 v2 = *(const uint4*)(xB + (size_t)s2 * D + c * 8);
                const uint4 v3 = *(const uint4*)(xB + (size_t)s3 * D + c * 8);
                ACCUM(v0) ACCUM(v1) ACCUM(v2) ACCUM(v3)
            }
            for (; j < end; ++j) {
                const uint4 v0 = *(const uint4*)(xB + (size_t)sh_s[j] * D + c * 8);
                ACCUM(v0)
            }

            uint4 o;
            o.x = ((unsigned)f2bf(accH[0] * inv) << 16) | f2bf(accL[0] * inv);
            o.y = ((unsigned)f2bf(accH[1] * inv) << 16) | f2bf(accL[1] * inv);
            o.z = ((unsigned)f2bf(accH[2] * inv) << 16) | f2bf(accL[2] * inv);
            o.w = ((unsigned)f2bf(accH[3] * inv) << 16) | f2bf(accL[3] * inv);
            // row ld (256 B stride), chunk c, XOR-swizzled per row
            const int byte = (c * 16) ^ ((ld & 7) << 4);
            *(uint4*)((char*)agg + ld * 256 + byte) = o;
        }
        __syncthreads();

        // MFMA pass: K-quarter q = kb q*4 .. q*4+3
        #pragma unroll
        for (int kbl = 0; kbl < 4; ++kbl) {
            short8 a[2];
            #pragma unroll
            for (int rt = 0; rt < 2; ++rt) {
                const int row  = rt * 16 + lrow;
                const int byte = (kbl * 64 + quad * 16) ^ ((row & 7) << 4);
                a[rt] = *(const short8*)((const char*)agg + row * 256 + byte);
            }
            const int kb = q * 4 + kbl;
            const unsigned short* wp = Wsw + ((size_t)(kb * 8 + ct0) * 64 + l) * 8;
            const short8 b0 = *(const short8*)wp;
            const short8 b1 = *(const short8*)(wp + 64 * 8);
            acc[0][0] = __builtin_amdgcn_mfma_f32_16x16x32_bf16(a[0], b0, acc[0][0], 0, 0, 0);
            acc[1][0] = __builtin_amdgcn_mfma_f32_16x16x32_bf16(a[1], b0, acc[1][0], 0, 0, 0);
            acc[0][1] = __builtin_amdgcn_mfma_f32_16x16x32_bf16(a[0], b1, acc[0][1], 0, 0, 0);
            acc[1][1] = __builtin_amdgcn_mfma_f32_16x16x32_bf16(a[1], b1, acc[1][1], 0, 0, 0);
        }
    }
    #undef ACCUM

    // ---- epilogue: bias + ReLU + store ----
    #pragma unroll
    for (int ci = 0; ci < 2; ++ci) {
        const int col = (ct0 + ci) * 16 + lrow;
        const float bv = bsum[col];
        #pragma unroll
        for (int rt = 0; rt < 2; ++rt) {
            #pragma unroll
            for (int e = 0; e < 4; ++e) {
                const int row = dst0 + rt * 16 + quad * 4 + e;
                if (row < N)
                    out[(size_t)row * D + col] = fmaxf(acc[rt][ci][e] + bv, 0.f);
            }
        }
    }
}

static inline size_t align_up(size_t v, size_t a) { return (v + a - 1) & ~(a - 1); }

extern "C" void kernel_launch(void* const* d_in, const int* in_sizes, int n_in,
                              void* d_out, int out_size, void* d_ws, size_t ws_size,
                              hipStream_t stream)
{
    const float* x    = (const float*)d_in[0];   // [N, 128]
    const float* W    = (const float*)d_in[1];   // [4, 128, 128]
    const float* bias = (const float*)d_in[2];   // [4, 128]
    const int* src    = (const int*)d_in[3];     // [4, E]
    const int* dst    = (const int*)d_in[4];     // [4, E]
    float* out        = (float*)d_out;           // [N, 128]

    const int N = in_sizes[0] / D;               // 100000
    const int E = in_sizes[3] / NREL;            // 500000
    const int nG = NREL * N;                     // 400000 buckets
    const int totalE = NREL * E;                 // 2000000 edges
    const int nbins  = (nG + NBK - 1) >> BINSHIFT;  // 3125

    char* w = (char*)d_ws;
    int* binCnt = (int*)w;            w += align_up((size_t)nbins * BPAD * 4, 256);
    unsigned int* part = (unsigned int*)w;     w += align_up((size_t)nbins * BCAP * 4, 256);
    unsigned short* Wsw = (unsigned short*)w;  w += align_up((size_t)512 * D * 2, 256);
    float* bsum = (float*)w;          w += align_up((size_t)D * 4, 256);
    unsigned short* xB = (unsigned short*)w;   // [N][128] bf16

    const int p1_blocks = 512;                   // 512 x 1024 thr = 2 blocks/CU

    hipMemsetAsync(binCnt, 0, (size_t)nbins * BPAD * sizeof(int), stream);
    part1prep_kernel<<<p1_blocks, 1024, 0, stream>>>(
        x, W, bias, src, dst, binCnt, part, xB, Wsw, bsum, E, N, nbins, totalE);
    agg_gemm_kernel<<<nbins, 256, 0, stream>>>(part, binCnt, xB, Wsw, bsum, out, N);
}

// Round 12
// 260.263 us; speedup vs baseline: 1.0218x; 1.0218x over previous
//
#include <hip/hip_runtime.h>

#define D 128          // D_IN == D_OUT == 128
#define NREL 4
#define BINSHIFT 8     // 256 buckets per coarse bin (r9 config — best total)
#define NBK 256        // buckets per bin
#define BCAP 1664      // edge capacity per bin window (mean 1280, +10.7 sigma)
#define BPAD 32        // ints per counter slot (128 B = 1 L2 line; r5/r6: same-
                       // line atomics serialize ~225 cy EACH, latency not tput)
#define NSCAT 256      // scatter blocks (1024 thr = 16 waves each) — r9 best
#define KPT 8          // edges/thread, register-carried between passes
#define NBINS_MAX 1600

typedef __attribute__((ext_vector_type(8))) short short8;
typedef __attribute__((ext_vector_type(4))) float f32x4;

static __device__ inline unsigned short f2bf(float f) {
    unsigned int u = __float_as_uint(f);
    u += 0x7fffu + ((u >> 16) & 1u);   // round-to-nearest-even
    return (unsigned short)(u >> 16);
}

// ---------------------------------------------------------------------------
// part1 + prep — EXACT round-9 version (best measured total, 240 us).
// Two-pass batched scatter, 1024-thread blocks, register-carried entries.
// ---------------------------------------------------------------------------
__global__ __launch_bounds__(1024) void part1prep_kernel(
    const float* __restrict__ x,      // [N][128]
    const float* __restrict__ W,      // [4][128][128]
    const float* __restrict__ bias,   // [4][128]
    const int* __restrict__ src, const int* __restrict__ dst,
    int* __restrict__ binCnt, unsigned int* __restrict__ part,
    unsigned short* __restrict__ xB,  // [N][128] bf16
    unsigned short* __restrict__ Wsw, // [16][8][64][8] bf16
    float* __restrict__ bsum,         // [128]
    int E, int N, int nbins, int total)
{
    __shared__ int hist[NBINS_MAX];   // 6.4 KB: count -> absolute cursor

    const int t     = threadIdx.x;
    const int gtid  = blockIdx.x * 1024 + t;
    const int gsize = gridDim.x * 1024;
    const int E2 = 2 * E, E3 = 3 * E;

    // ================= Phase A: batched scatter (blocks < NSCAT) ===========
    if (blockIdx.x < NSCAT) {
        const int chunk = (total + NSCAT - 1) / NSCAT;   // 7813
        const int e0 = blockIdx.x * chunk;
        const int n  = min(chunk, total - e0);

        for (int i = t; i < nbins; i += 1024) hist[i] = 0;
        __syncthreads();

        // pass 1: read once, decode, register-carry, count
        unsigned ebuf[KPT];
        int      bbuf[KPT];
        #pragma unroll
        for (int k = 0; k < KPT; ++k) {
            const int i = t + k * 1024;
            bbuf[k] = -1;
            if (i < n) {
                const int e = e0 + i;
                const int g = (dst[e] << 2) | ((e >= E) + (e >= E2) + (e >= E3));
                ebuf[k] = (unsigned)src[e] | ((unsigned)(g & (NBK - 1)) << 17);
                bbuf[k] = g >> BINSHIFT;
                atomicAdd(&hist[bbuf[k]], 1);
            }
        }
        __syncthreads();

        // reserve: one global atomic per non-empty bin -> ABSOLUTE cursor
        for (int b = t; b < nbins; b += 1024) {
            const int h = hist[b];
            hist[b] = h ? b * BCAP + atomicAdd(&binCnt[b * BPAD], h) : 0;
        }
        __syncthreads();

        // pass 2: place from registers
        #pragma unroll
        for (int k = 0; k < KPT; ++k) {
            if (bbuf[k] >= 0) {
                const int pos = atomicAdd(&hist[bbuf[k]], 1);    // LDS cursor
                if (pos < (bbuf[k] + 1) * BCAP)                  // 10.7-sigma guard
                    part[pos] = ebuf[k];
            }
        }
    }

    // ================= Phase B: prep (all blocks, grid-stride) ==============
    if (gtid < D)
        bsum[gtid] = bias[gtid] + bias[D + gtid] + bias[2 * D + gtid] + bias[3 * D + gtid];

    for (int gid = gtid; gid < 8192; gid += gsize) {
        const int l   = gid & 63;
        const int ct  = (gid >> 6) & 7;
        const int kb  = gid >> 9;
        const int rel = kb >> 2;
        const int kbase = (kb & 3) * 32 + (l >> 4) * 8;
        const int nn = ct * 16 + (l & 15);
        ushort4 v0, v1;
        const float* wp = W + (size_t)rel * D * D + (size_t)kbase * D + nn;
        v0.x = f2bf(wp[0 * D]); v0.y = f2bf(wp[1 * D]);
        v0.z = f2bf(wp[2 * D]); v0.w = f2bf(wp[3 * D]);
        v1.x = f2bf(wp[4 * D]); v1.y = f2bf(wp[5 * D]);
        v1.z = f2bf(wp[6 * D]); v1.w = f2bf(wp[7 * D]);
        ushort4* op = (ushort4*)(Wsw + (size_t)gid * 8);
        op[0] = v0;
        op[1] = v1;
    }

    const int n4 = N * D / 4;
    for (int i = gtid; i < n4; i += gsize) {
        const float4 v = ((const float4*)x)[i];
        ushort4 o;
        o.x = f2bf(v.x); o.y = f2bf(v.y); o.z = f2bf(v.z); o.w = f2bf(v.w);
        ((ushort4*)xB)[i] = o;
    }
}

// ---------------------------------------------------------------------------
// Fused aggregate + GEMM + bias + ReLU. ONE block per bin (M=64 dsts).
// r9 structure, ONE change: gather uses 8-lane teams, each lane owning TWO
// 16 B chunks (c8, c8+8). 32 teams = 32 buckets per (h,q) phase (no ld-loop);
// every edge issues 2 loads/lane even in the scalar tail -> 2x tail MLP.
// (r11 falsified the occupancy theory: +8% occ gave +0% BW; BW ~ MLP.)
// LDS 18.4 KB -> 8 blocks/CU (wave cap).
// ---------------------------------------------------------------------------
__global__ __launch_bounds__(256, 8) void agg_gemm_kernel(
    const unsigned int* __restrict__ part,
    const int* __restrict__ binCnt,
    const unsigned short* __restrict__ xB,   // [N][128] bf16
    const unsigned short* __restrict__ Wsw,  // [16][8][64][8] bf16
    const float* __restrict__ bsum,          // [128]
    float* __restrict__ out,                 // [N][128]
    int N)
{
    __shared__ int sh_s[BCAP];                         // 6.7 KB sorted src
    __shared__ int hist[NBK];                          // 1 KB
    __shared__ int scanbuf[NBK];                       // 1 KB
    __shared__ int offl[NBK + 1];                      // 1 KB
    __shared__ __align__(16) unsigned short agg[32 * 128];  // 8 KB, swizzled
    // phase-A overlay: raw entry staging in the idle agg region (6.7 <= 8 KB)
    unsigned int* raw = (unsigned int*)agg;

    const int t    = threadIdx.x;
    const int b    = blockIdx.x;
    const size_t base = (size_t)b * BCAP;
    const int cnt  = min(binCnt[b * BPAD], BCAP);
    const int dst0 = b * 64;

    // ---- A: histogram + raw staging (single part[] read) ----
    hist[t] = 0;
    __syncthreads();
    for (int i = t; i < cnt; i += 256) {
        const unsigned v = part[base + i];
        raw[i] = v;
        atomicAdd(&hist[v >> 17], 1);
    }
    __syncthreads();

    const int myc = hist[t];
    scanbuf[t] = myc;
    __syncthreads();
    for (int off = 1; off < 256; off <<= 1) {
        int v = (t >= off) ? scanbuf[t - off] : 0;
        __syncthreads();
        scanbuf[t] += v;
        __syncthreads();
    }
    offl[t] = scanbuf[t] - myc;
    if (t == 255) offl[256] = scanbuf[255];
    hist[t] = scanbuf[t] - myc;           // cursor
    __syncthreads();

    // sort: LDS raw -> LDS sh_s
    for (int i = t; i < cnt; i += 256) {
        const unsigned v = raw[i];
        const int pos = atomicAdd(&hist[v >> 17], 1);
        sh_s[pos] = (int)(v & 0x1FFFF);
    }
    __syncthreads();

    // ---- B/C: 2 halves x 4 rel-quarters of gather -> LDS -> MFMA ----
    const int c8   = t & 7;         // chunk-pair index: lane owns chunks c8, c8+8
    const int team = t >> 3;        // bucket slot 0..31

    const int wv   = t >> 6;
    const int l    = t & 63;
    const int lrow = l & 15;
    const int quad = l >> 4;
    const int ct0  = wv * 2;        // each wave: 2 col-tiles x 2 row-tiles

    // ACC(v, o): accumulate uint4 v (8 bf16) into aL/aH[o..o+3]
    #define ACC(v, o)                                         \
        aL[(o)+0] += __uint_as_float((v).x << 16);            \
        aH[(o)+0] += __uint_as_float((v).x & 0xffff0000u);    \
        aL[(o)+1] += __uint_as_float((v).y << 16);            \
        aH[(o)+1] += __uint_as_float((v).y & 0xffff0000u);    \
        aL[(o)+2] += __uint_as_float((v).z << 16);            \
        aH[(o)+2] += __uint_as_float((v).z & 0xffff0000u);    \
        aL[(o)+3] += __uint_as_float((v).w << 16);            \
        aH[(o)+3] += __uint_as_float((v).w & 0xffff0000u);

    #pragma unroll 1
    for (int h = 0; h < 2; ++h) {
        f32x4 acc[2][2] = {};

        #pragma unroll 1
        for (int q = 0; q < NREL; ++q) {
            if (h | q) __syncthreads();   // previous MFMA pass done with agg

            // gather: team owns bucket (h*32+team)*4+q; lane covers 32 B
            {
                const int bkt = (h * 32 + team) * 4 + q;
                const int beg = offl[bkt];
                const int end = offl[bkt + 1];
                const float inv = 1.0f / fmaxf((float)(end - beg), 1.0f);

                float aL[8], aH[8];
                #pragma unroll
                for (int z = 0; z < 8; ++z) { aL[z] = 0.f; aH[z] = 0.f; }

                int j = beg;
                for (; j + 1 < end; j += 2) {
                    const int s0 = sh_s[j];
                    const int s1 = sh_s[j + 1];
                    const unsigned short* p0 = xB + (size_t)s0 * D + c8 * 8;
                    const unsigned short* p1 = xB + (size_t)s1 * D + c8 * 8;
                    const uint4 v0a = *(const uint4*)(p0);
                    const uint4 v0b = *(const uint4*)(p0 + 64);
                    const uint4 v1a = *(const uint4*)(p1);
                    const uint4 v1b = *(const uint4*)(p1 + 64);
                    ACC(v0a, 0) ACC(v0b, 4) ACC(v1a, 0) ACC(v1b, 4)
                }
                if (j < end) {
                    const unsigned short* p0 = xB + (size_t)sh_s[j] * D + c8 * 8;
                    const uint4 v0a = *(const uint4*)(p0);
                    const uint4 v0b = *(const uint4*)(p0 + 64);
                    ACC(v0a, 0) ACC(v0b, 4)
                }

                uint4 o0, o1;
                o0.x = ((unsigned)f2bf(aH[0] * inv) << 16) | f2bf(aL[0] * inv);
                o0.y = ((unsigned)f2bf(aH[1] * inv) << 16) | f2bf(aL[1] * inv);
                o0.z = ((unsigned)f2bf(aH[2] * inv) << 16) | f2bf(aL[2] * inv);
                o0.w = ((unsigned)f2bf(aH[3] * inv) << 16) | f2bf(aL[3] * inv);
                o1.x = ((unsigned)f2bf(aH[4] * inv) << 16) | f2bf(aL[4] * inv);
                o1.y = ((unsigned)f2bf(aH[5] * inv) << 16) | f2bf(aL[5] * inv);
                o1.z = ((unsigned)f2bf(aH[6] * inv) << 16) | f2bf(aL[6] * inv);
                o1.w = ((unsigned)f2bf(aH[7] * inv) << 16) | f2bf(aL[7] * inv);
                // row = team (256 B stride), chunks c8 and c8+8, XOR-swizzled
                const int sw = (team & 7) << 4;
                *(uint4*)((char*)agg + team * 256 + ((c8 * 16) ^ sw)) = o0;
                *(uint4*)((char*)agg + team * 256 + (((c8 + 8) * 16) ^ sw)) = o1;
            }
            __syncthreads();

            // MFMA pass: K-quarter q = kb q*4 .. q*4+3, rows of half h
            #pragma unroll
            for (int kbl = 0; kbl < 4; ++kbl) {
                short8 a[2];
                #pragma unroll
                for (int rt = 0; rt < 2; ++rt) {
                    const int row  = rt * 16 + lrow;
                    const int byte = (kbl * 64 + quad * 16) ^ ((row & 7) << 4);
                    a[rt] = *(const short8*)((const char*)agg + row * 256 + byte);
                }
                const int kb = q * 4 + kbl;
                const unsigned short* wp = Wsw + ((size_t)(kb * 8 + ct0) * 64 + l) * 8;
                const short8 b0 = *(const short8*)wp;
                const short8 b1 = *(const short8*)(wp + 64 * 8);
                acc[0][0] = __builtin_amdgcn_mfma_f32_16x16x32_bf16(a[0], b0, acc[0][0], 0, 0, 0);
                acc[1][0] = __builtin_amdgcn_mfma_f32_16x16x32_bf16(a[1], b0, acc[1][0], 0, 0, 0);
                acc[0][1] = __builtin_amdgcn_mfma_f32_16x16x32_bf16(a[0], b1, acc[0][1], 0, 0, 0);
                acc[1][1] = __builtin_amdgcn_mfma_f32_16x16x32_bf16(a[1], b1, acc[1][1], 0, 0, 0);
            }
        }

        // ---- epilogue for half h: bias + ReLU + store ----
        #pragma unroll
        for (int ci = 0; ci < 2; ++ci) {
            const int col = (ct0 + ci) * 16 + lrow;
            const float bv = bsum[col];
            #pragma unroll
            for (int rt = 0; rt < 2; ++rt) {
                #pragma unroll
                for (int e = 0; e < 4; ++e) {
                    const int row = dst0 + h * 32 + rt * 16 + quad * 4 + e;
                    if (row < N)
                        out[(size_t)row * D + col] = fmaxf(acc[rt][ci][e] + bv, 0.f);
                }
            }
        }
    }
    #undef ACC
}

static inline size_t align_up(size_t v, size_t a) { return (v + a - 1) & ~(a - 1); }

extern "C" void kernel_launch(void* const* d_in, const int* in_sizes, int n_in,
                              void* d_out, int out_size, void* d_ws, size_t ws_size,
                              hipStream_t stream)
{
    const float* x    = (const float*)d_in[0];   // [N, 128]
    const float* W    = (const float*)d_in[1];   // [4, 128, 128]
    const float* bias = (const float*)d_in[2];   // [4, 128]
    const int* src    = (const int*)d_in[3];     // [4, E]
    const int* dst    = (const int*)d_in[4];     // [4, E]
    float* out        = (float*)d_out;           // [N, 128]

    const int N = in_sizes[0] / D;               // 100000
    const int E = in_sizes[3] / NREL;            // 500000
    const int nG = NREL * N;                     // 400000 buckets
    const int totalE = NREL * E;                 // 2000000 edges
    const int nbins  = (nG + NBK - 1) >> BINSHIFT;  // 1563

    char* w = (char*)d_ws;
    int* binCnt = (int*)w;            w += align_up((size_t)nbins * BPAD * 4, 256);
    unsigned int* part = (unsigned int*)w;     w += align_up((size_t)nbins * BCAP * 4, 256);
    unsigned short* Wsw = (unsigned short*)w;  w += align_up((size_t)512 * D * 2, 256);
    float* bsum = (float*)w;          w += align_up((size_t)D * 4, 256);
    unsigned short* xB = (unsigned short*)w;   // [N][128] bf16

    const int p1_blocks = 512;                   // 512 x 1024 thr = 32 waves/CU

    hipMemsetAsync(binCnt, 0, (size_t)nbins * BPAD * sizeof(int), stream);
    part1prep_kernel<<<p1_blocks, 1024, 0, stream>>>(
        x, W, bias, src, dst, binCnt, part, xB, Wsw, bsum, E, N, nbins, totalE);
    agg_gemm_kernel<<<nbins, 256, 0, stream>>>(part, binCnt, xB, Wsw, bsum, out, N);
}

// Round 14
// 239.762 us; speedup vs baseline: 1.1092x; 1.0855x over previous
//
#include <hip/hip_runtime.h>

#define D 128          // D_IN == D_OUT == 128
#define NREL 4
#define BINSHIFT 8     // 256 buckets per coarse bin (r9 config — best total)
#define NBK 256        // buckets per bin
#define BCAP 1664      // edge capacity per bin window (mean 1280, +10.7 sigma)
#define BPAD 32        // ints per counter slot (128 B = 1 L2 line; r5/r6: same-
                       // line atomics serialize ~225 cy EACH, latency not tput)
#define NSCAT 256      // scatter blocks (1024 thr = 16 waves each) — r9 best
#define NBINS_MAX 1600

typedef __attribute__((ext_vector_type(8))) short short8;
typedef __attribute__((ext_vector_type(4))) float f32x4;

static __device__ inline unsigned short f2bf(float f) {
    unsigned int u = __float_as_uint(f);
    u += 0x7fffu + ((u >> 16) & 1u);   // round-to-nearest-even
    return (unsigned short)(u >> 16);
}

// ---------------------------------------------------------------------------
// part1 + prep — round-9 structure (best measured total, 240 us) with the
// register-carry SPILL FIX: r9's ebuf[8]/bbuf[8] arrays compiled to scratch
// (VGPR_Count=12 proved it — rule: indexed arrays demote to local memory).
// Named scalars via unrolled macro keep the 16 values in VGPRs, removing a
// ~32 MB scratch round-trip from part1's critical path.
// ---------------------------------------------------------------------------
__global__ __launch_bounds__(1024) void part1prep_kernel(
    const float* __restrict__ x,      // [N][128]
    const float* __restrict__ W,      // [4][128][128]
    const float* __restrict__ bias,   // [4][128]
    const int* __restrict__ src, const int* __restrict__ dst,
    int* __restrict__ binCnt, unsigned int* __restrict__ part,
    unsigned short* __restrict__ xB,  // [N][128] bf16
    unsigned short* __restrict__ Wsw, // [16][8][64][8] bf16
    float* __restrict__ bsum,         // [128]
    int E, int N, int nbins, int total)
{
    __shared__ int hist[NBINS_MAX];   // 6.4 KB: count -> absolute cursor

    const int t     = threadIdx.x;
    const int gtid  = blockIdx.x * 1024 + t;
    const int gsize = gridDim.x * 1024;
    const int E2 = 2 * E, E3 = 3 * E;

    // ================= Phase A: batched scatter (blocks < NSCAT) ===========
    if (blockIdx.x < NSCAT) {
        const int chunk = (total + NSCAT - 1) / NSCAT;   // 7813
        const int eBase = blockIdx.x * chunk;
        const int n  = min(chunk, total - eBase);

        for (int i = t; i < nbins; i += 1024) hist[i] = 0;
        __syncthreads();

        // pass 1: read once, decode, carry in NAMED registers, count
        unsigned ev0, ev1, ev2, ev3, ev4, ev5, ev6, ev7;
        int      bv0, bv1, bv2, bv3, bv4, bv5, bv6, bv7;

        #define P1(k, ev, bv)                                                 \
        {   const int i = t + (k) * 1024;                                     \
            (bv) = -1; (ev) = 0;                                              \
            if (i < n) {                                                      \
                const int e = eBase + i;                                      \
                const int g = (dst[e] << 2) |                                 \
                              ((e >= E) + (e >= E2) + (e >= E3));             \
                (ev) = (unsigned)src[e] | ((unsigned)(g & (NBK - 1)) << 17);  \
                (bv) = g >> BINSHIFT;                                         \
                atomicAdd(&hist[(bv)], 1);                                    \
            } }
        P1(0, ev0, bv0) P1(1, ev1, bv1) P1(2, ev2, bv2) P1(3, ev3, bv3)
        P1(4, ev4, bv4) P1(5, ev5, bv5) P1(6, ev6, bv6) P1(7, ev7, bv7)
        #undef P1
        __syncthreads();

        // reserve: one global atomic per non-empty bin -> ABSOLUTE cursor
        for (int b = t; b < nbins; b += 1024) {
            const int h = hist[b];
            hist[b] = h ? b * BCAP + atomicAdd(&binCnt[b * BPAD], h) : 0;
        }
        __syncthreads();

        // pass 2: place from registers
        #define P2(ev, bv)                                                    \
        {   if ((bv) >= 0) {                                                  \
                const int pos = atomicAdd(&hist[(bv)], 1);  /* LDS cursor */  \
                if (pos < ((bv) + 1) * BCAP)             /* 10.7-sigma */     \
                    part[pos] = (ev);                                         \
            } }
        P2(ev0, bv0) P2(ev1, bv1) P2(ev2, bv2) P2(ev3, bv3)
        P2(ev4, bv4) P2(ev5, bv5) P2(ev6, bv6) P2(ev7, bv7)
        #undef P2
    }

    // ================= Phase B: prep (all blocks, grid-stride) ==============
    if (gtid < D)
        bsum[gtid] = bias[gtid] + bias[D + gtid] + bias[2 * D + gtid] + bias[3 * D + gtid];

    for (int gid = gtid; gid < 8192; gid += gsize) {
        const int l   = gid & 63;
        const int ct  = (gid >> 6) & 7;
        const int kb  = gid >> 9;
        const int rel = kb >> 2;
        const int kbase = (kb & 3) * 32 + (l >> 4) * 8;
        const int nn = ct * 16 + (l & 15);
        ushort4 v0, v1;
        const float* wp = W + (size_t)rel * D * D + (size_t)kbase * D + nn;
        v0.x = f2bf(wp[0 * D]); v0.y = f2bf(wp[1 * D]);
        v0.z = f2bf(wp[2 * D]); v0.w = f2bf(wp[3 * D]);
        v1.x = f2bf(wp[4 * D]); v1.y = f2bf(wp[5 * D]);
        v1.z = f2bf(wp[6 * D]); v1.w = f2bf(wp[7 * D]);
        ushort4* op = (ushort4*)(Wsw + (size_t)gid * 8);
        op[0] = v0;
        op[1] = v1;
    }

    const int n4 = N * D / 4;
    for (int i = gtid; i < n4; i += gsize) {
        const float4 v = ((const float4*)x)[i];
        ushort4 o;
        o.x = f2bf(v.x); o.y = f2bf(v.y); o.z = f2bf(v.z); o.w = f2bf(v.w);
        ((ushort4*)xB)[i] = o;
    }
}

// ---------------------------------------------------------------------------
// Fused aggregate + GEMM + bias + ReLU. ONE block per bin (M=64 dsts).
// EXACT round-9 version (92.5 us warm, 2.79e8 B — the traffic floor of all
// gather shapes tried; r12's 8-lane-team variant raised BW to 3.36 TB/s but
// raised traffic 40% — reverted).
// ---------------------------------------------------------------------------
__global__ __launch_bounds__(256, 8) void agg_gemm_kernel(
    const unsigned int* __restrict__ part,
    const int* __restrict__ binCnt,
    const unsigned short* __restrict__ xB,   // [N][128] bf16
    const unsigned short* __restrict__ Wsw,  // [16][8][64][8] bf16
    const float* __restrict__ bsum,          // [128]
    float* __restrict__ out,                 // [N][128]
    int N)
{
    __shared__ int sh_s[BCAP];                         // 6.7 KB sorted src
    __shared__ int hist[NBK];                          // 1 KB
    __shared__ int scanbuf[NBK];                       // 1 KB
    __shared__ int offl[NBK + 1];                      // 1 KB
    __shared__ __align__(16) unsigned short agg[32 * 128];  // 8 KB, swizzled
    // phase-A overlay: raw entry staging in the idle agg region (6.7 <= 8 KB)
    unsigned int* raw = (unsigned int*)agg;

    const int t    = threadIdx.x;
    const int b    = blockIdx.x;
    const size_t base = (size_t)b * BCAP;
    const int cnt  = min(binCnt[b * BPAD], BCAP);
    const int dst0 = b * 64;

    // ---- A: histogram + raw staging (single part[] read) ----
    hist[t] = 0;
    __syncthreads();
    for (int i = t; i < cnt; i += 256) {
        const unsigned v = part[base + i];
        raw[i] = v;
        atomicAdd(&hist[v >> 17], 1);
    }
    __syncthreads();

    const int myc = hist[t];
    scanbuf[t] = myc;
    __syncthreads();
    for (int off = 1; off < 256; off <<= 1) {
        int v = (t >= off) ? scanbuf[t - off] : 0;
        __syncthreads();
        scanbuf[t] += v;
        __syncthreads();
    }
    offl[t] = scanbuf[t] - myc;
    if (t == 255) offl[256] = scanbuf[255];
    hist[t] = scanbuf[t] - myc;           // cursor
    __syncthreads();

    // sort: LDS raw -> LDS sh_s
    for (int i = t; i < cnt; i += 256) {
        const unsigned v = raw[i];
        const int pos = atomicAdd(&hist[v >> 17], 1);
        sh_s[pos] = (int)(v & 0x1FFFF);
    }
    __syncthreads();

    // ---- B/C: 2 halves x 4 rel-quarters of gather -> LDS -> MFMA ----
    const int c    = t & 15;        // 16-byte chunk index (8 bf16)
    const int team = t >> 4;        // unit slot 0..15

    const int wv   = t >> 6;
    const int l    = t & 63;
    const int lrow = l & 15;
    const int quad = l >> 4;
    const int ct0  = wv * 2;        // each wave: 2 col-tiles x 2 row-tiles

    #define ACCUM(v)                                        \
        accL[0] += __uint_as_float((v).x << 16);            \
        accH[0] += __uint_as_float((v).x & 0xffff0000u);    \
        accL[1] += __uint_as_float((v).y << 16);            \
        accH[1] += __uint_as_float((v).y & 0xffff0000u);    \
        accL[2] += __uint_as_float((v).z << 16);            \
        accH[2] += __uint_as_float((v).z & 0xffff0000u);    \
        accL[3] += __uint_as_float((v).w << 16);            \
        accH[3] += __uint_as_float((v).w & 0xffff0000u);

    #pragma unroll 1
    for (int h = 0; h < 2; ++h) {
        f32x4 acc[2][2] = {};

        #pragma unroll 1
        for (int q = 0; q < NREL; ++q) {
            if (h | q) __syncthreads();   // previous MFMA pass done with agg

            // gather: 32 buckets of half h, rel q (bucket = (h*32+ld)*4+q)
            for (int ld = team; ld < 32; ld += 16) {
                const int bkt = (h * 32 + ld) * 4 + q;
                const int beg = offl[bkt];
                const int end = offl[bkt + 1];
                const float inv = 1.0f / fmaxf((float)(end - beg), 1.0f);

                float accL[4] = {0.f, 0.f, 0.f, 0.f};
                float accH[4] = {0.f, 0.f, 0.f, 0.f};

                int j = beg;
                for (; j + 3 < end; j += 4) {
                    const int s0 = sh_s[j];
                    const int s1 = sh_s[j + 1];
                    const int s2 = sh_s[j + 2];
                    const int s3 = sh_s[j + 3];
                    const uint4 v0 = *(const uint4*)(xB + (size_t)s0 * D + c * 8);
                    const uint4 v1 = *(const uint4*)(xB + (size_t)s1 * D + c * 8);
                    const uint4 v2 = *(const uint4*)(xB + (size_t)s2 * D + c * 8);
                    const uint4 v3 = *(const uint4*)(xB + (size_t)s3 * D + c * 8);
                    ACCUM(v0) ACCUM(v1) ACCUM(v2) ACCUM(v3)
                }
                for (; j < end; ++j) {
                    const uint4 v0 = *(const uint4*)(xB + (size_t)sh_s[j] * D + c * 8);
                    ACCUM(v0)
                }

                uint4 o;
                o.x = ((unsigned)f2bf(accH[0] * inv) << 16) | f2bf(accL[0] * inv);
                o.y = ((unsigned)f2bf(accH[1] * inv) << 16) | f2bf(accL[1] * inv);
                o.z = ((unsigned)f2bf(accH[2] * inv) << 16) | f2bf(accL[2] * inv);
                o.w = ((unsigned)f2bf(accH[3] * inv) << 16) | f2bf(accL[3] * inv);
                // row ld (256 B stride), chunk c, XOR-swizzled per row
                const int byte = (c * 16) ^ ((ld & 7) << 4);
                *(uint4*)((char*)agg + ld * 256 + byte) = o;
            }
            __syncthreads();

            // MFMA pass: K-quarter q = kb q*4 .. q*4+3, rows of half h
            #pragma unroll
            for (int kbl = 0; kbl < 4; ++kbl) {
                short8 a[2];
                #pragma unroll
                for (int rt = 0; rt < 2; ++rt) {
                    const int row  = rt * 16 + lrow;
                    const int byte = (kbl * 64 + quad * 16) ^ ((row & 7) << 4);
                    a[rt] = *(const short8*)((const char*)agg + row * 256 + byte);
                }
                const int kb = q * 4 + kbl;
                const unsigned short* wp = Wsw + ((size_t)(kb * 8 + ct0) * 64 + l) * 8;
                const short8 b0 = *(const short8*)wp;
                const short8 b1 = *(const short8*)(wp + 64 * 8);
                acc[0][0] = __builtin_amdgcn_mfma_f32_16x16x32_bf16(a[0], b0, acc[0][0], 0, 0, 0);
                acc[1][0] = __builtin_amdgcn_mfma_f32_16x16x32_bf16(a[1], b0, acc[1][0], 0, 0, 0);
                acc[0][1] = __builtin_amdgcn_mfma_f32_16x16x32_bf16(a[0], b1, acc[0][1], 0, 0, 0);
                acc[1][1] = __builtin_amdgcn_mfma_f32_16x16x32_bf16(a[1], b1, acc[1][1], 0, 0, 0);
            }
        }

        // ---- epilogue for half h: bias + ReLU + store ----
        #pragma unroll
        for (int ci = 0; ci < 2; ++ci) {
            const int col = (ct0 + ci) * 16 + lrow;
            const float bv = bsum[col];
            #pragma unroll
            for (int rt = 0; rt < 2; ++rt) {
                #pragma unroll
                for (int e = 0; e < 4; ++e) {
                    const int row = dst0 + h * 32 + rt * 16 + quad * 4 + e;
                    if (row < N)
                        out[(size_t)row * D + col] = fmaxf(acc[rt][ci][e] + bv, 0.f);
                }
            }
        }
    }
    #undef ACCUM
}

static inline size_t align_up(size_t v, size_t a) { return (v + a - 1) & ~(a - 1); }

extern "C" void kernel_launch(void* const* d_in, const int* in_sizes, int n_in,
                              void* d_out, int out_size, void* d_ws, size_t ws_size,
                              hipStream_t stream)
{
    const float* x    = (const float*)d_in[0];   // [N, 128]
    const float* W    = (const float*)d_in[1];   // [4, 128, 128]
    const float* bias = (const float*)d_in[2];   // [4, 128]
    const int* src    = (const int*)d_in[3];     // [4, E]
    const int* dst    = (const int*)d_in[4];     // [4, E]
    float* out        = (float*)d_out;           // [N, 128]

    const int N = in_sizes[0] / D;               // 100000
    const int E = in_sizes[3] / NREL;            // 500000
    const int nG = NREL * N;                     // 400000 buckets
    const int totalE = NREL * E;                 // 2000000 edges
    const int nbins  = (nG + NBK - 1) >> BINSHIFT;  // 1563

    char* w = (char*)d_ws;
    int* binCnt = (int*)w;            w += align_up((size_t)nbins * BPAD * 4, 256);
    unsigned int* part = (unsigned int*)w;     w += align_up((size_t)nbins * BCAP * 4, 256);
    unsigned short* Wsw = (unsigned short*)w;  w += align_up((size_t)512 * D * 2, 256);
    float* bsum = (float*)w;          w += align_up((size_t)D * 4, 256);
    unsigned short* xB = (unsigned short*)w;   // [N][128] bf16

    const int p1_blocks = 512;                   // 512 x 1024 thr = 32 waves/CU

    hipMemsetAsync(binCnt, 0, (size_t)nbins * BPAD * sizeof(int), stream);
    part1prep_kernel<<<p1_blocks, 1024, 0, stream>>>(
        x, W, bias, src, dst, binCnt, part, xB, Wsw, bsum, E, N, nbins, totalE);
    agg_gemm_kernel<<<nbins, 256, 0, stream>>>(part, binCnt, xB, Wsw, bsum, out, N);
}